// Round 2
// baseline (9.879 us; speedup 1.0000x reference)
//
#include <hip/hip_runtime.h>

// Z1_Layer_start: closed-form sparse fill of (AA[85,70,70], -b[85], A0[70,70]).
// Only v1, t, H1, c are used; rho1, mu1 are dead inputs.
//
// Structure: one block per 70x70 slice (85) + one block for (b, A0).
// Phase 1: block zero-fills its region (float4). Phase 2 (after barrier):
// only candidate nonzero positions are computed and overwritten.

#define MDIM   70
#define SLICE  (MDIM * MDIM)          // 4900 floats = 1225 float4, 16B-aligned per slice
#define AA_ELEMS (85 * SLICE)         // 416500
#define B_OFF    AA_ELEMS
#define A0_OFF   (AA_ELEMS + 85)      // 416585
#define TOT      (A0_OFF + SLICE)     // 421485

__constant__ int c_ones[16] = {0,8,15,21,26,30,33,35,36,44,51,57,62,66,69,71};
__constant__ int c_diag[7]  = {8,17,61,63,65,67,69};

// candidate m (or n) index for symmetric slices, computed arithmetically
__device__ __forceinline__ int candf(int sel, int i, int j, int base4) {
    if (sel < 12) {
        int b = (sel * 11) >> 5;          // sel/3 for sel<12
        int r = sel - 3 * b;
        return 9 * b + (r == 0 ? i : (r == 1 ? j : 8));
    }
    if (sel == 12) return base4 + i;
    if (sel == 13) return base4 + j;
    return 54 + sel;                      // 14->68, 15->69
}

__global__ __launch_bounds__(512) void z1_sparse_kernel(
    const float* __restrict__ v1,   // 4
    const float* __restrict__ t,    // 4
    const float* __restrict__ H1,   // 8x8 row-major
    const float* __restrict__ c,    // 1
    float* __restrict__ out)
{
    const int k   = blockIdx.x;     // 0..85
    const int tid = threadIdx.x;

    // ---------- Phase 1: zero-fill this block's region ----------
    if (k < 85) {
        float4* base = (float4*)(out + k * SLICE);   // k*19600 bytes, 16B-aligned
        for (int ch = tid; ch < 1225; ch += 512)
            base[ch] = make_float4(0.f, 0.f, 0.f, 0.f);
    } else {
        // region [416500, 421485): 4985 floats = 1246 float4 + 1 scalar tail
        float4* base = (float4*)(out + B_OFF);       // 1666000 bytes, 16B-aligned
        for (int ch = tid; ch < 1246; ch += 512)
            base[ch] = make_float4(0.f, 0.f, 0.f, 0.f);
        if (tid == 0) out[TOT - 1] = 1.0f;           // A0[69][69] = 1 (not negated)
    }
    __syncthreads();

    // ---------- Phase 2: sparse value writes ----------
    if (k < 72) {
        // symmetric einsum slices: AA[k] = -Asvec/Bsvec[k]
        if (tid >= 256) return;
        const bool isB = (k >= 36);
        int kk = isB ? (k - 36) : k;
        int i = 0;
        while (kk >= 8 - i) { kk -= 8 - i; ++i; }    // triu_indices(8) decode
        const int j = i + kk;
        const int base4 = isB ? 44 : 36;

        const int m = candf(tid >> 4, i, j, base4);
        const int n = candf(tid & 15, i, j, base4);

        // h columns of H = 0.2*H1: cols {0,2,5,7}
        float hiv[4], hjv[4];
        hiv[0] = 0.2f * H1[i * 8 + 0];  hjv[0] = 0.2f * H1[j * 8 + 0];
        hiv[1] = 0.2f * H1[i * 8 + 2];  hjv[1] = 0.2f * H1[j * 8 + 2];
        hiv[2] = 0.2f * H1[i * 8 + 5];  hjv[2] = 0.2f * H1[j * 8 + 5];
        hiv[3] = 0.2f * H1[i * 8 + 7];  hjv[3] = 0.2f * H1[j * 8 + 7];

        float aij = 0.0f, aji = 0.0f;
        #pragma unroll
        for (int b = 0; b < 4; ++b) {
            // cA = {0.1,-1,-1,-1}; cB = {-1,0.1,-1,-1}
            float cb = (!isB ? (b == 0) : (b == 1)) ? 0.1f : -1.0f;
            int off = 9 * b;       // {0,9,18,27}
            int cor = 9 * b + 8;   // {8,17,26,35}
            float uim = (m == off + i ? 1.0f : 0.0f) + (m == cor ? hiv[b] : 0.0f);
            float ujn = (n == off + j ? 1.0f : 0.0f) + (n == cor ? hjv[b] : 0.0f);
            float ujm = (m == off + j ? 1.0f : 0.0f) + (m == cor ? hjv[b] : 0.0f);
            float uin = (n == off + i ? 1.0f : 0.0f) + (n == cor ? hiv[b] : 0.0f);
            aij += cb * uim * ujn;
            aji += cb * ujm * uin;
        }
        if (m == base4 + i && n == base4 + j) aij += 1.0f;   // b=4 delta term
        if (m == base4 + j && n == base4 + i) aji += 1.0f;
        if (i == j && ((m == 68 && n == 69) || (m == 69 && n == 68))) {
            aij += 1.0f;  aji += 1.0f;                       // I8[i,j]*D6869
        }
        const float s = (i == j) ? 0.5f : 1.0f;
        out[k * SLICE + m * MDIM + n] = -((aij + aji) * s);
    } else if (k < 85) {
        // A2 slices (negated)
        const int k2 = k - 72;
        const int bse = k * SLICE;
        if (k2 < 4) {
            const int lo = 9 * k2;                    // {0,9,18,27}
            if (tid < 8)       out[bse + (lo + tid) * 71] = -400.0f;
            else if (tid == 8) out[bse + (lo + 8) * 71]   =  1.0f;   // -(-1)
            else if (tid == 9) out[bse + (52 + k2) * 71]  = -1.0f;
        } else if (k2 < 8) {
            const int q = k2 - 4;
            const int cpos = 9 * q + 8;               // {8,17,26,35}
            const int bb = 60 + 2 * q;
            const float csgn = (q < 2) ? -1.0f : 1.0f;
            if (tid == 0)      out[bse + cpos * 71]          = -csgn;
            else if (tid == 1) out[bse + (56 + q) * 71]      = -1.0f;
            else if (tid == 2) out[bse + bb * MDIM + bb + 1] = -1.0f;
            else if (tid == 3) out[bse + (bb + 1) * MDIM + bb] = -1.0f;
        } else if (k2 < 12) {
            const int p = 60 + 2 * (k2 - 8);          // {60,62,64,66}
            if (tid == 0) out[bse + p * 71] = -1.0f;
        } else {
            if (tid == 0) out[bse + 68 * 71] = -1.0f;
        }
    } else {
        // ---- -b (85) and A0 (70x70, not negated) ----
        if (tid < 16) {
            out[B_OFF + c_ones[tid]] = -1.0f;
        } else if (tid < 20) {
            out[B_OFF + 76 + (tid - 16)] = -v1[tid - 16];
        } else if (tid < 25) {
            out[B_OFF + 80 + (tid - 20)] = -0.5f * c[0];
        } else if (tid < 32) {
            const int p = c_diag[tid - 25];
            out[A0_OFF + p * 71] = (p == 8 || p == 17) ? -0.0004f : 1.0f;
        } else if (tid < 40) {
            const int e = tid - 32;                   // 0..7
            const int q = e >> 1;                     // 0..3
            const int row = 60 + 2 * q, col = row + 1;
            const float tv = t[q ^ 2];                // perm {2,3,0,1}
            if (e & 1) out[A0_OFF + col * MDIM + row] = tv;
            else       out[A0_OFF + row * MDIM + col] = tv;
        }
    }
}

extern "C" void kernel_launch(void* const* d_in, const int* in_sizes, int n_in,
                              void* d_out, int out_size, void* d_ws, size_t ws_size,
                              hipStream_t stream) {
    // setup_inputs order: rho1(0), mu1(1), v1(2), t(3), H1(4), c(5)
    const float* v1 = (const float*)d_in[2];
    const float* t  = (const float*)d_in[3];
    const float* H1 = (const float*)d_in[4];
    const float* c  = (const float*)d_in[5];
    float* out = (float*)d_out;

    z1_sparse_kernel<<<86, 512, 0, stream>>>(v1, t, H1, c, out);
}